// Round 5
// baseline (115.404 us; speedup 1.0000x reference)
//
#include <hip/hip_runtime.h>

#define PP 7        // PH == PW == 7
#define KK 6        // K
#define SCALE_F 0.0625f
#define XMAX 40     // aligned x footprint cap (mult of 4; true max span 37+3 align)
#define YMAX 40     // y footprint cap (true max span 37)
#define CG  4       // channels per block

__global__ __launch_bounds__(256) void prroi_fwd(
    const float* __restrict__ feats, const float* __restrict__ rois,
    float* __restrict__ out, int C, int H, int W)
{
    __shared__ float sWy[PP][KK + 1];
    __shared__ float sWx[PP][KK + 1];
    __shared__ int   sGy[PP][KK + 1];
    __shared__ int   sGx[PP][KK + 1];
    __shared__ __align__(16) float sP[CG][YMAX][XMAX];  // raw unique patch
    __shared__ __align__(16) float sT[CG][PP][XMAX];    // y-reduced intermediate
    __shared__ float sInv;
    __shared__ int   sBn;

    const int n  = blockIdx.x;
    const int c0 = blockIdx.y * CG;
    const int t  = threadIdx.x;

    // ---- per-roi separable weights (threads 0..14) ----
    if (t < 14) {
        const float* r = rois + (size_t)n * 5;
        const int axis = (t < PP) ? 0 : 1;   // 0 = y, 1 = x
        const int p    = axis ? (t - PP) : t;
        float start, end; int size;
        if (axis == 0) { start = r[2] * SCALE_F; end = r[4] * SCALE_F; size = H; }
        else           { start = r[1] * SCALE_F; end = r[3] * SCALE_F; size = W; }
        const float length = fmaxf(end - start, 0.0f);
        const float binsz  = length / (float)PP;
        const float ws = start + binsz * (float)p;
        const float we = ws + binsz;
        const float s  = floorf(ws);
        float w[KK + 1];
        #pragma unroll
        for (int k = 0; k <= KK; ++k) w[k] = 0.0f;
        #pragma unroll
        for (int k = 0; k < KK; ++k) {
            const float cell = s + (float)k;
            if (cell < we) {                       // strict, matches reference
                const float x0 = fmaxf(ws, cell);
                const float x1 = fminf(we, cell + 1.0f);
                const float a0 = x0 - cell, l0 = x1 - cell;
                w[k]     += l0 - 0.5f * l0 * l0 - a0 + 0.5f * a0 * a0;
                const float a1 = cell + 1.0f - x1, l1 = cell + 1.0f - x0;
                w[k + 1] += l1 - 0.5f * l1 * l1 - a1 + 0.5f * a1 * a1;
            }
        }
        const int si = (int)s;
        #pragma unroll
        for (int k = 0; k <= KK; ++k) {
            const int  idx   = si + k;
            const bool valid = (idx >= 0) && (idx < size);
            const float wv   = valid ? w[k] : 0.0f;
            const int   ic   = min(max(idx, 0), size - 1);
            if (axis == 0) { sWy[p][k] = wv; sGy[p][k] = ic; }
            else           { sWx[p][k] = wv; sGx[p][k] = ic; }
        }
    } else if (t == 14) {
        const float* r = rois + (size_t)n * 5;
        sBn = (int)r[0];
        const float bw  = fmaxf((r[3] - r[1]) * SCALE_F, 0.0f) / (float)PP;
        const float bh  = fmaxf((r[4] - r[2]) * SCALE_F, 0.0f) / (float)PP;
        const float win = bw * bh;
        sInv = (win > 0.0f) ? (1.0f / fmaxf(win, 1e-12f)) : 0.0f;
    }
    __syncthreads();

    const int bn = sBn;
    const int HW = H * W;
    // clamped indices are monotone -> min/max at corners
    const int y0    = sGy[0][0];
    const int spanY = min(sGy[PP - 1][KK] - y0 + 1, YMAX);
    const int x0a   = sGx[0][0] & ~3;                    // 16B-aligned window start
    const int G     = min(((sGx[PP - 1][KK] - x0a + 1) + 3) >> 2, XMAX / 4);

    // ---- phase 1: stage unique patch global -> LDS (zero redundancy) ----
    // W % 4 == 0 => aligned slots past W-4 hold only never-referenced columns,
    // so the tail clamp cannot displace referenced data.
    const float* fbase = feats + (size_t)(bn * C + c0) * HW;
    const int totalS = CG * spanY * G;
    for (int idx = t; idx < totalS; idx += 256) {
        const int g  = idx % G;
        const int yy = (idx / G) % spanY;
        const int cl = idx / (G * spanY);
        const int xcol = min(x0a + 4 * g, W - 4);
        const float4 v = *(const float4*)(fbase + (size_t)cl * HW + (y0 + yy) * W + xcol);
        ((float4*)&sP[cl][yy][0])[g] = v;
    }
    __syncthreads();

    // ---- phase 2: y-reduction from LDS ----
    const int totalY = CG * PP * G;
    for (int idx = t; idx < totalY; idx += 256) {
        const int g  = idx % G;
        const int i  = (idx / G) % PP;
        const int cl = idx / (G * PP);
        float4 acc = make_float4(0.f, 0.f, 0.f, 0.f);
        #pragma unroll
        for (int a = 0; a <= KK; ++a) {
            const float wy = sWy[i][a];
            const float4 v = ((const float4*)&sP[cl][sGy[i][a] - y0][0])[g];
            acc.x = fmaf(wy, v.x, acc.x);
            acc.y = fmaf(wy, v.y, acc.y);
            acc.z = fmaf(wy, v.z, acc.z);
            acc.w = fmaf(wy, v.w, acc.w);
        }
        ((float4*)&sT[cl][i][0])[g] = acc;
    }
    __syncthreads();

    // ---- phase 3: x-reduction from LDS ----
    const float inv = sInv;
    for (int o = t; o < CG * PP * PP; o += 256) {
        const int j  = o % PP;
        const int i  = (o / PP) % PP;
        const int cl = o / (PP * PP);
        float acc = 0.0f;
        #pragma unroll
        for (int b = 0; b <= KK; ++b)
            acc = fmaf(sWx[j][b], sT[cl][i][sGx[j][b] - x0a], acc);
        out[((size_t)n * C + c0 + cl) * (PP * PP) + i * PP + j] = acc * inv;
    }
}

extern "C" void kernel_launch(void* const* d_in, const int* in_sizes, int n_in,
                              void* d_out, int out_size, void* d_ws, size_t ws_size,
                              hipStream_t stream) {
    const float* feats = (const float*)d_in[0];
    const float* rois  = (const float*)d_in[1];
    float* out = (float*)d_out;

    const int C = 64, H = 200, W = 304;
    const int N = in_sizes[1] / 5;

    dim3 grid(N, C / CG), block(256);
    hipLaunchKernelGGL(prroi_fwd, grid, block, 0, stream,
                       feats, rois, out, C, H, W);
}

// Round 6
// 101.962 us; speedup vs baseline: 1.1318x; 1.1318x over previous
//
#include <hip/hip_runtime.h>

#define PP 7        // PH == PW == 7
#define KK 6        // K
#define SCALE_F 0.0625f
#define XMAX 40     // aligned x footprint cap (mult of 4; true max 37+3 align)
#define CG  8       // channels per block

__global__ __launch_bounds__(256) void prroi_fwd(
    const float* __restrict__ feats, const float* __restrict__ rois,
    float* __restrict__ out, int C, int H, int W)
{
    __shared__ float sW[4][14][8];                      // per-wave weights (y:0-6, x:7-13)
    __shared__ int   sG[4][14][8];                      // per-wave indices (x stored rel)
    __shared__ __align__(16) float sT[CG][PP][XMAX];    // y-reduced intermediate

    const int n    = blockIdx.x;
    const int c0   = blockIdx.y * CG;
    const int t    = threadIdx.x;
    const int wave = t >> 6, lane = t & 63;

    // ---- wave-uniform scalars (every lane computes; SGPR math) ----
    const float* r = rois + (size_t)n * 5;
    const float rx1 = r[1] * SCALE_F, ry1 = r[2] * SCALE_F;
    const float rx2 = r[3] * SCALE_F, ry2 = r[4] * SCALE_F;
    const int   bn  = (int)r[0];
    const float bw  = fmaxf(rx2 - rx1, 0.0f) / (float)PP;
    const float bh  = fmaxf(ry2 - ry1, 0.0f) / (float)PP;
    const float win = bw * bh;
    const float inv = (win > 0.0f) ? (1.0f / fmaxf(win, 1e-12f)) : 0.0f;
    // x window: floor(ws(p)) is monotone in p; corners give min/max (matches ref clip)
    const int x0a  = (min(max((int)floorf(rx1), 0), W - 1)) & ~3;          // 16B aligned
    const int xmax = min(max((int)floorf(rx1 + bw * (float)(PP - 1)) + KK, 0), W - 1);
    const int G    = ((xmax - x0a + 1) + 3) >> 2;   // float4 slots per row, 1..10
    const int R    = 64 / G;                         // rows per wave-load

    // ---- per-wave weight prologue (lanes 0..13, all waves in parallel) ----
    if (lane < 14) {
        const int  axis  = (lane >= PP) ? 1 : 0;     // 0=y, 1=x
        const int  p     = axis ? lane - PP : lane;
        const float start = axis ? rx1 : ry1;
        const float binsz = axis ? bw  : bh;
        const int   size  = axis ? W   : H;
        const float ws = start + binsz * (float)p;
        const float we = ws + binsz;
        const float s  = floorf(ws);
        float w[KK + 1];
        #pragma unroll
        for (int k = 0; k <= KK; ++k) w[k] = 0.0f;
        #pragma unroll
        for (int k = 0; k < KK; ++k) {
            const float cell = s + (float)k;
            if (cell < we) {                         // strict, matches reference
                const float x0 = fmaxf(ws, cell);
                const float x1 = fminf(we, cell + 1.0f);
                const float a0 = x0 - cell, l0 = x1 - cell;
                w[k]     += l0 - 0.5f * l0 * l0 - a0 + 0.5f * a0 * a0;
                const float a1 = cell + 1.0f - x1, l1 = cell + 1.0f - x0;
                w[k + 1] += l1 - 0.5f * l1 * l1 - a1 + 0.5f * a1 * a1;
            }
        }
        const int si = (int)s;
        #pragma unroll
        for (int k = 0; k <= KK; ++k) {
            const int  idx   = si + k;
            const bool valid = (idx >= 0) && (idx < size);
            int ic = min(max(idx, 0), size - 1);
            if (axis) ic -= x0a;                     // x: store relative to window
            sW[wave][lane][k] = valid ? w[k] : 0.0f;
            sG[wave][lane][k] = ic;
        }
    }
    __syncthreads();

    // ---- pass 1: y-reduction, fixed-i lanes, weights hoisted to registers ----
    const int HW  = H * W;
    const int rr  = lane / G;
    const int g   = lane - rr * G;
    const int xcol = min(x0a + 4 * g, W - 4);        // aligned tail clamp (W%4==0)
    if (rr < R) {
        const int q  = wave * R + rr;                // q < 4R, 4R >= 24 covers i 0..6
        const int i  = q % 7;
        const int Pi = (4 * R + 6 - i) / 7;          // cl stride for this residue
        int cl = q / 7;
        if (cl < CG) {
            float wy[KK + 1]; int ro[KK + 1];
            #pragma unroll
            for (int a = 0; a <= KK; ++a) {
                wy[a] = sW[wave][i][a];
                ro[a] = sG[wave][i][a] * W;
            }
            const float* base0 = feats + (size_t)(bn * C + c0) * HW + xcol;
            for (; cl < CG; cl += Pi) {
                const float* base = base0 + (size_t)cl * HW;
                float4 acc = make_float4(0.f, 0.f, 0.f, 0.f);
                #pragma unroll
                for (int a = 0; a <= KK; ++a) {
                    const float4 v = *(const float4*)(base + ro[a]);
                    acc.x = fmaf(wy[a], v.x, acc.x);
                    acc.y = fmaf(wy[a], v.y, acc.y);
                    acc.z = fmaf(wy[a], v.z, acc.z);
                    acc.w = fmaf(wy[a], v.w, acc.w);
                }
                ((float4*)&sT[cl][i][0])[g] = acc;
            }
        }
    }
    __syncthreads();

    // ---- pass 2: x-reduction from LDS ----
    for (int o = t; o < CG * PP * PP; o += 256) {
        const int j  = o % PP;
        const int i  = (o / PP) % PP;
        const int cl = o / (PP * PP);
        float acc = 0.0f;
        #pragma unroll
        for (int b = 0; b <= KK; ++b)
            acc = fmaf(sW[wave][PP + j][b], sT[cl][i][sG[wave][PP + j][b]], acc);
        out[((size_t)n * C + c0 + cl) * (PP * PP) + i * PP + j] = acc * inv;
    }
}

extern "C" void kernel_launch(void* const* d_in, const int* in_sizes, int n_in,
                              void* d_out, int out_size, void* d_ws, size_t ws_size,
                              hipStream_t stream) {
    const float* feats = (const float*)d_in[0];
    const float* rois  = (const float*)d_in[1];
    float* out = (float*)d_out;

    const int C = 64, H = 200, W = 304;
    const int N = in_sizes[1] / 5;

    dim3 grid(N, C / CG), block(256);
    hipLaunchKernelGGL(prroi_fwd, grid, block, 0, stream,
                       feats, rois, out, C, H, W);
}